// Round 1
// baseline (364.292 us; speedup 1.0000x reference)
//
#include <hip/hip_runtime.h>

typedef __attribute__((ext_vector_type(4))) float f32x4;
typedef __attribute__((ext_vector_type(8))) short s16x8;
typedef __attribute__((ext_vector_type(4))) short s16x4;
typedef unsigned short u16;

#define T_SEQ 2048
#define EMB   2048
#define NHEAD 16
#define G32   32
#define DH    64
#define DV    128
#define NEGV  (-1e9f)
// LAMBDA_INIT = 0.8 - 0.6*exp(-0.3*12)
#define LAMBDA_INIT 0.7836057665316245f
#define SCALING 0.125f

__device__ __forceinline__ u16 f2bf(float f) {
    unsigned int u = __builtin_bit_cast(unsigned int, f);
    unsigned int r = (u + 0x7fffu + ((u >> 16) & 1u)) >> 16;
    return (u16)r;
}

// ---------------- lambda scalar ----------------
__global__ void k_lambda(const float* lq1, const float* lk1,
                         const float* lq2, const float* lk2, float* lam) {
    int l = threadIdx.x;  // 64
    float a = lq1[l] * lk1[l];
    float b = lq2[l] * lk2[l];
    for (int m = 32; m; m >>= 1) { a += __shfl_xor(a, m); b += __shfl_xor(b, m); }
    if (l == 0) *lam = __expf(a) - __expf(b) + LAMBDA_INIT;
}

// ---------------- rope tables (2048 x 32) ----------------
__global__ void k_ropetab(float* cost, float* sint) {
    int i = blockIdx.x * 256 + threadIdx.x;  // 65536
    int j = i & 31, t = i >> 5;
    double invf = exp(-(double)j * (9.210340371976184 / 32.0));  // 10000^(-j/32)
    double fr = (double)t * invf;
    cost[i] = (float)cos(fr);
    sint[i] = (float)sin(fr);
}

// ---------------- x fp32 -> bf16 ----------------
__global__ void k_cvt_x(const float* __restrict__ in, u16* __restrict__ out) {
    int i = blockIdx.x * 256 + threadIdx.x;  // one per 4 elems
    f32x4 v = *(const f32x4*)(in + (size_t)i * 4);
    s16x4 o;
    for (int j = 0; j < 4; j++) o[j] = (short)f2bf(v[j]);
    *(s16x4*)(out + (size_t)i * 4) = o;
}

// ---------------- 2048x2048 fp32 -> transposed bf16 ----------------
__global__ __launch_bounds__(256)
void k_transpose_cvt(const float* __restrict__ in, u16* __restrict__ out) {
    __shared__ float tile[32][33];
    int lc = threadIdx.x & 31;
    int lr0 = (threadIdx.x >> 5) * 4;
    int col = blockIdx.x * 32 + lc;
    int row0 = blockIdx.y * 32 + lr0;
    for (int r = 0; r < 4; r++)
        tile[lr0 + r][lc] = in[(size_t)(row0 + r) * 2048 + col];
    __syncthreads();
    int ncol = blockIdx.y * 32 + lc;
    int nrow0 = blockIdx.x * 32 + lr0;
    for (int r = 0; r < 4; r++)
        out[(size_t)(nrow0 + r) * 2048 + ncol] = f2bf(tile[lc][lr0 + r]);
}

// ---------------- GEMM: C(2048x2048) = A(bf16,row) @ Bt(bf16, n-major)^T ------
// MODE 0: write fp32 C.  MODE 1: rope+scale -> bf16 (g,t,d).  MODE 2: rope -> bf16.
template <int MODE>
__global__ __launch_bounds__(256)
void k_gemm(const u16* __restrict__ A, const u16* __restrict__ Bt,
            float* __restrict__ Cf, u16* __restrict__ Cb,
            const float* __restrict__ costab, const float* __restrict__ sintab) {
    __shared__ u16 As[128][40];
    __shared__ u16 Bs[128][40];
    int t0 = blockIdx.y * 128, n0 = blockIdx.x * 128;
    int tid = threadIdx.x;
    int lane = tid & 63, wid = tid >> 6;
    int wm = wid >> 1, wn = wid & 1;
    int rl = lane & 15, rg = lane >> 4;
    int srow = tid >> 2;          // 0..63
    int scol = (tid & 3) * 8;     // 0,8,16,24
    f32x4 acc[4][4] = {};
    for (int k0 = 0; k0 < 2048; k0 += 32) {
        __syncthreads();
        const u16* pa = A + (size_t)(t0 + srow) * 2048 + k0 + scol;
        s16x8 va0 = *(const s16x8*)pa;
        s16x8 va1 = *(const s16x8*)(pa + (size_t)64 * 2048);
        const u16* pb = Bt + (size_t)(n0 + srow) * 2048 + k0 + scol;
        s16x8 vb0 = *(const s16x8*)pb;
        s16x8 vb1 = *(const s16x8*)(pb + (size_t)64 * 2048);
        *(s16x8*)&As[srow][scol] = va0;
        *(s16x8*)&As[srow + 64][scol] = va1;
        *(s16x8*)&Bs[srow][scol] = vb0;
        *(s16x8*)&Bs[srow + 64][scol] = vb1;
        __syncthreads();
        s16x8 af[4], bfr[4];
        for (int i = 0; i < 4; i++) af[i] = *(const s16x8*)&As[wm * 64 + i * 16 + rl][rg * 8];
        for (int j = 0; j < 4; j++) bfr[j] = *(const s16x8*)&Bs[wn * 64 + j * 16 + rl][rg * 8];
        for (int i = 0; i < 4; i++)
            for (int j = 0; j < 4; j++)
                acc[i][j] = __builtin_amdgcn_mfma_f32_16x16x32_bf16(af[i], bfr[j], acc[i][j], 0, 0, 0);
    }
    // epilogue
    for (int i = 0; i < 4; i++) {
        int trow = t0 + wm * 64 + i * 16 + rg * 4;
        for (int j = 0; j < 4; j++) {
            int col = n0 + wn * 64 + j * 16 + rl;
            if (MODE == 0) {
                for (int r = 0; r < 4; r++)
                    Cf[(size_t)(trow + r) * 2048 + col] = acc[i][j][r];
            } else {
                int g = (n0 + wn * 64) >> 6;     // wave's 64 cols = one sub-head
                int d = j * 16 + rl;             // 0..63
                int jp = j ^ 2;                  // paired fragment (d +/- 32)
                float sgn = (j < 2) ? -1.f : 1.f;
                for (int r = 0; r < 4; r++) {
                    int t = trow + r;
                    float c = costab[t * 32 + (d & 31)];
                    float s = sintab[t * 32 + (d & 31)];
                    float v = acc[i][j][r] * c + sgn * acc[i][jp][r] * s;
                    if (MODE == 1) v *= SCALING;
                    Cb[((size_t)g * 2048 + t) * 64 + d] = f2bf(v);
                }
            }
        }
    }
}

// ---------------- differential flash attention ----------------
// grid (16 qblk, 32 g), 256 threads (4 waves x 32 q-rows).
__global__ __launch_bounds__(256)
void k_flash(const u16* __restrict__ qb, const u16* __restrict__ kb,
             const u16* __restrict__ vt, float* __restrict__ O) {
    __shared__ u16 Kt[64][72];
    __shared__ u16 Vt[128][72];
    __shared__ u16 Pb[4][32][72];
    int qblk = blockIdx.x;
    int g = blockIdx.y;
    int h = g >> 1;
    int tid = threadIdx.x, lane = tid & 63, wid = tid >> 6;
    int q0 = qblk * 128, q0w = q0 + wid * 32;
    int rl = lane & 15, rg = lane >> 4;
    // Q fragments in registers
    s16x8 aQ[2][2];
    for (int mf = 0; mf < 2; mf++)
        for (int ks = 0; ks < 2; ks++)
            aQ[mf][ks] = *(const s16x8*)(qb + ((size_t)(g * 2048 + q0w + mf * 16 + rl)) * 64 + ks * 32 + rg * 8);
    f32x4 Oa[2][8] = {};
    float mrow[2][4], lrow[2][4];
    for (int mf = 0; mf < 2; mf++)
        for (int r = 0; r < 4; r++) { mrow[mf][r] = -3e38f; lrow[mf][r] = 0.f; }
    int ntiles = (q0 + 128) >> 6;
    int srow = tid >> 3;          // 0..31
    int scol = (tid & 7) * 8;     // 0..56
    for (int it = 0; it < ntiles; it++) {
        int kv0 = it * 64;
        __syncthreads();
        for (int p = 0; p < 2; p++) {
            int r = srow + p * 32;
            *(s16x8*)&Kt[r][scol] = *(const s16x8*)(kb + ((size_t)(g * 2048 + kv0 + r)) * 64 + scol);
        }
        for (int p = 0; p < 4; p++) {
            int dv = srow + p * 32;
            *(s16x8*)&Vt[dv][scol] = *(const s16x8*)(vt + ((size_t)(h * 128 + dv)) * 2048 + kv0 + scol);
        }
        __syncthreads();
        s16x8 bK[4][2];
        for (int nf = 0; nf < 4; nf++)
            for (int ks = 0; ks < 2; ks++)
                bK[nf][ks] = *(const s16x8*)&Kt[nf * 16 + rl][ks * 32 + rg * 8];
        f32x4 S[2][4];
        for (int mf = 0; mf < 2; mf++)
            for (int nf = 0; nf < 4; nf++) {
                f32x4 s = {};
                s = __builtin_amdgcn_mfma_f32_16x16x32_bf16(aQ[mf][0], bK[nf][0], s, 0, 0, 0);
                s = __builtin_amdgcn_mfma_f32_16x16x32_bf16(aQ[mf][1], bK[nf][1], s, 0, 0, 0);
                S[mf][nf] = s;
            }
        for (int mf = 0; mf < 2; mf++) {
            float nm[4];
            for (int r = 0; r < 4; r++) {
                int q = q0w + mf * 16 + rg * 4 + r;
                float mx = -3e38f;
                for (int nf = 0; nf < 4; nf++) {
                    int kv = kv0 + nf * 16 + rl;
                    float v = S[mf][nf][r];
                    v = (kv > q) ? NEGV : v;
                    S[mf][nf][r] = v;
                    mx = fmaxf(mx, v);
                }
                for (int msk = 1; msk < 16; msk <<= 1) mx = fmaxf(mx, __shfl_xor(mx, msk));
                nm[r] = fmaxf(mrow[mf][r], mx);
                float sc = __expf(mrow[mf][r] - nm[r]);
                mrow[mf][r] = nm[r];
                lrow[mf][r] *= sc;
                for (int nf = 0; nf < 8; nf++) Oa[mf][nf][r] *= sc;
            }
            for (int r = 0; r < 4; r++) {
                float rs = 0.f;
                for (int nf = 0; nf < 4; nf++) {
                    float p = __expf(S[mf][nf][r] - nm[r]);
                    S[mf][nf][r] = p;
                    rs += p;
                }
                for (int msk = 1; msk < 16; msk <<= 1) rs += __shfl_xor(rs, msk);
                lrow[mf][r] += rs;
            }
            for (int nf = 0; nf < 4; nf++)
                for (int r = 0; r < 4; r++)
                    Pb[wid][mf * 16 + rg * 4 + r][nf * 16 + rl] = f2bf(S[mf][nf][r]);
        }
        __syncthreads();
        s16x8 aP[2][2];
        for (int mf = 0; mf < 2; mf++)
            for (int ks = 0; ks < 2; ks++)
                aP[mf][ks] = *(const s16x8*)&Pb[wid][mf * 16 + rl][ks * 32 + rg * 8];
        for (int ks = 0; ks < 2; ks++)
            for (int nf = 0; nf < 8; nf++) {
                s16x8 bV = *(const s16x8*)&Vt[nf * 16 + rl][ks * 32 + rg * 8];
                for (int mf = 0; mf < 2; mf++)
                    Oa[mf][nf] = __builtin_amdgcn_mfma_f32_16x16x32_bf16(aP[mf][ks], bV, Oa[mf][nf], 0, 0, 0);
            }
    }
    for (int mf = 0; mf < 2; mf++)
        for (int r = 0; r < 4; r++) {
            float inv = 1.f / lrow[mf][r];
            int t = q0w + mf * 16 + rg * 4 + r;
            for (int nf = 0; nf < 8; nf++)
                O[((size_t)(g * 2048 + t)) * 128 + nf * 16 + rl] = Oa[mf][nf][r] * inv;
        }
}

// ---------------- combine O0 - lam*O1, RMSNorm, -> bf16 (t, e) ----------------
__global__ __launch_bounds__(256)
void k_combine(const float* __restrict__ O, const float* __restrict__ lamp,
               const float* __restrict__ subw, u16* __restrict__ Ab) {
    int gw = blockIdx.x * 4 + (threadIdx.x >> 6);  // 0..32767
    int lane = threadIdx.x & 63;
    int h = gw >> 11;
    int t = gw & 2047;
    float lam = *lamp;
    const float* o0 = O + ((size_t)((2 * h) * 2048 + t)) * 128;
    const float* o1 = O + ((size_t)((2 * h + 1) * 2048 + t)) * 128;
    float a0 = o0[lane * 2] - lam * o1[lane * 2];
    float a1 = o0[lane * 2 + 1] - lam * o1[lane * 2 + 1];
    float ss = a0 * a0 + a1 * a1;
    for (int m = 1; m < 64; m <<= 1) ss += __shfl_xor(ss, m);
    float inv = rsqrtf(ss * (1.f / 128.f) + 1e-5f) * (1.f - LAMBDA_INIT);
    a0 *= inv * subw[lane * 2];
    a1 *= inv * subw[lane * 2 + 1];
    unsigned int pk = (unsigned int)f2bf(a0) | ((unsigned int)f2bf(a1) << 16);
    *(unsigned int*)(Ab + (size_t)t * 2048 + h * 128 + lane * 2) = pk;
}

extern "C" void kernel_launch(void* const* d_in, const int* in_sizes, int n_in,
                              void* d_out, int out_size, void* d_ws, size_t ws_size,
                              hipStream_t stream) {
    const float* x    = (const float*)d_in[0];
    const float* Wq   = (const float*)d_in[2];
    const float* Wk   = (const float*)d_in[3];
    const float* Wv   = (const float*)d_in[4];
    const float* Wo   = (const float*)d_in[5];
    const float* lq1  = (const float*)d_in[6];
    const float* lk1  = (const float*)d_in[7];
    const float* lq2  = (const float*)d_in[8];
    const float* lk2  = (const float*)d_in[9];
    const float* subw = (const float*)d_in[10];
    float* out = (float*)d_out;

    char* ws = (char*)d_ws;
    size_t off = 0;
    auto alloc = [&](size_t sz) -> char* {
        char* p = ws + off;
        off = (off + sz + 255) & ~(size_t)255;
        return p;
    };
    float* lam  = (float*)alloc(4);
    float* cost = (float*)alloc((size_t)T_SEQ * 32 * 4);
    float* sint = (float*)alloc((size_t)T_SEQ * 32 * 4);
    u16* xbf  = (u16*)alloc((size_t)T_SEQ * EMB * 2);
    u16* wqt  = (u16*)alloc((size_t)EMB * EMB * 2);
    u16* wkt  = (u16*)alloc((size_t)EMB * EMB * 2);
    u16* wvt  = (u16*)alloc((size_t)EMB * EMB * 2);
    u16* wot  = (u16*)alloc((size_t)EMB * EMB * 2);
    u16* qbf  = (u16*)alloc((size_t)G32 * T_SEQ * DH * 2);
    u16* kbf  = (u16*)alloc((size_t)G32 * T_SEQ * DH * 2);
    u16* vtb  = (u16*)alloc((size_t)NHEAD * DV * T_SEQ * 2);
    float* Obuf = (float*)alloc((size_t)G32 * T_SEQ * DV * 4);
    u16* Abf  = (u16*)alloc((size_t)T_SEQ * EMB * 2);
    float* vraw = (float*)Obuf;  // alias: vraw fully consumed before Obuf is written

    k_lambda<<<1, 64, 0, stream>>>(lq1, lk1, lq2, lk2, lam);
    k_ropetab<<<256, 256, 0, stream>>>(cost, sint);
    k_cvt_x<<<4096, 256, 0, stream>>>(x, xbf);
    dim3 tg(64, 64);
    k_transpose_cvt<<<tg, 256, 0, stream>>>(Wq, wqt);
    k_transpose_cvt<<<tg, 256, 0, stream>>>(Wk, wkt);
    k_transpose_cvt<<<tg, 256, 0, stream>>>(Wv, wvt);
    k_transpose_cvt<<<tg, 256, 0, stream>>>(Wo, wot);
    dim3 gg(16, 16);
    k_gemm<1><<<gg, 256, 0, stream>>>(xbf, wqt, nullptr, qbf, cost, sint);
    k_gemm<2><<<gg, 256, 0, stream>>>(xbf, wkt, nullptr, kbf, cost, sint);
    k_gemm<0><<<gg, 256, 0, stream>>>(xbf, wvt, vraw, nullptr, nullptr, nullptr);
    k_transpose_cvt<<<tg, 256, 0, stream>>>(vraw, vtb);
    k_flash<<<dim3(16, 32), 256, 0, stream>>>(qbf, kbf, vtb, Obuf);
    k_combine<<<8192, 256, 0, stream>>>(Obuf, lam, subw, Abf);
    k_gemm<0><<<gg, 256, 0, stream>>>(Abf, wot, out, nullptr, nullptr, nullptr);
}